// Round 1
// baseline (1084.933 us; speedup 1.0000x reference)
//
#include <hip/hip_runtime.h>
#include <hip/hip_bf16.h>

#define B_  8
#define S_  512
#define D_  1024
#define H_  16
#define DK_ 64
#define TB_ 64
#define SCALE_ 0.125f      // DK^-0.5

// ---------------------------------------------------------------------------
// GEMM: C = A(4096x1024) @ W(1024x1024) + bias(1024)
// BM=128, BN=64, BK=16, 256 threads, 8x4 micro-tile per thread.
// WRITE_QKV=1: scatter output to (B,H,S,DK) layout; else plain row-major.
// ---------------------------------------------------------------------------
template<int WRITE_QKV>
__global__ __launch_bounds__(256)
void gemm_kernel(const float* __restrict__ A, const float* __restrict__ W,
                 const float* __restrict__ bias, float* __restrict__ C)
{
    __shared__ float As[128][17];   // +1 pad: conflict-free column reads
    __shared__ float Ws[16][64];    // unpadded: float4 row reads
    const int tid  = threadIdx.x;
    const int tx   = tid & 15;      // n dir
    const int ty   = tid >> 4;      // m dir
    const int row0 = blockIdx.x * 128;
    const int col0 = blockIdx.y * 64;

    float acc[8][4] = {};

    for (int k0 = 0; k0 < D_; k0 += 16) {
        #pragma unroll
        for (int u0 = 0; u0 < 2; ++u0) {
            int u  = tid + u0 * 256;           // 512 float4 units of 128x16
            int r  = u >> 2;
            int c4 = (u & 3) << 2;
            float4 a4 = *(const float4*)&A[(size_t)(row0 + r) * D_ + k0 + c4];
            As[r][c4+0] = a4.x; As[r][c4+1] = a4.y;
            As[r][c4+2] = a4.z; As[r][c4+3] = a4.w;
        }
        {
            int r  = tid >> 4;
            int c4 = (tid & 15) << 2;
            *(float4*)&Ws[r][c4] =
                *(const float4*)&W[(size_t)(k0 + r) * D_ + col0 + c4];
        }
        __syncthreads();
        #pragma unroll
        for (int kk = 0; kk < 16; ++kk) {
            float4 w4 = *(const float4*)&Ws[kk][tx << 2];
            #pragma unroll
            for (int i = 0; i < 8; ++i) {
                float a = As[ty * 8 + i][kk];
                acc[i][0] = fmaf(a, w4.x, acc[i][0]);
                acc[i][1] = fmaf(a, w4.y, acc[i][1]);
                acc[i][2] = fmaf(a, w4.z, acc[i][2]);
                acc[i][3] = fmaf(a, w4.w, acc[i][3]);
            }
        }
        __syncthreads();
    }

    float4 b4 = *(const float4*)&bias[col0 + (tx << 2)];
    #pragma unroll
    for (int i = 0; i < 8; ++i) {
        int m = row0 + ty * 8 + i;
        float4 o = { acc[i][0] + b4.x, acc[i][1] + b4.y,
                     acc[i][2] + b4.z, acc[i][3] + b4.w };
        if (WRITE_QKV) {
            int bb = m >> 9, ss = m & 511;
            int n  = col0 + (tx << 2);
            int hh = n >> 6, dd = n & 63;
            *(float4*)&C[((size_t)((bb * H_ + hh) * S_ + ss)) * DK_ + dd] = o;
        } else {
            *(float4*)&C[(size_t)m * D_ + col0 + (tx << 2)] = o;
        }
    }
}

// ---------------------------------------------------------------------------
// Temporal bias: bias[b,i,j] = MLP(1/log(e + tm[b,i,j]))  (head-independent,
// computed ONCE here instead of H=16 times inside attention)
// ---------------------------------------------------------------------------
__global__ __launch_bounds__(256)
void tbias_kernel(const float* __restrict__ tm, const float* __restrict__ w1,
                  const float* __restrict__ b1, const float* __restrict__ w2,
                  const float* __restrict__ b2, float* __restrict__ bias)
{
    __shared__ float sw1[TB_], sb1[TB_], sw2[TB_];
    if (threadIdx.x < TB_) {
        sw1[threadIdx.x] = w1[threadIdx.x];
        sb1[threadIdx.x] = b1[threadIdx.x];
        sw2[threadIdx.x] = w2[threadIdx.x];
    }
    __syncthreads();
    const float ec  = 2.7182818284590452f;
    const float b2v = b2[0];
    const int n = B_ * S_ * S_;
    for (int i = blockIdx.x * blockDim.x + threadIdx.x; i < n;
         i += gridDim.x * blockDim.x) {
        float t   = 1.0f / logf(ec + tm[i]);
        float acc = b2v;
        #pragma unroll
        for (int j = 0; j < TB_; ++j) {
            float h = fmaf(t, sw1[j], sb1[j]);
            h = (h >= 0.f) ? h : 0.2f * h;
            acc = fmaf(h, sw2[j], acc);
        }
        bias[i] = acc;
    }
}

// ---------------------------------------------------------------------------
// Attention: one block per (b, h, 32-query tile). 256 threads.
// Thread (qrow = tid>>3, sub = tid&7): 8 threads cooperate per query row.
// Causal tile-skipping: only key tiles kt <= (q0+31)/64 are processed.
// ---------------------------------------------------------------------------
__global__ __launch_bounds__(256)
void attn_kernel(const float* __restrict__ q, const float* __restrict__ k,
                 const float* __restrict__ v, const float* __restrict__ bias,
                 const int* __restrict__ pmask, float* __restrict__ attn)
{
    __shared__ float ks[64][68];    // stride 68: b128 reads conflict-free
    __shared__ float vs[64][64];
    __shared__ float sc[32][520];   // stride 520: <=2-way on all phases
    __shared__ int   msk[S_];

    const int tid = threadIdx.x;
    const int qt  = blockIdx.x;           // 0..15
    const int h   = blockIdx.y;
    const int b   = blockIdx.z;
    const int q0  = qt * 32;

    const float* qbase = q + ((size_t)(b * H_ + h) * S_ + q0) * DK_;
    const float* kbase = k + ((size_t)(b * H_ + h) * S_) * DK_;
    const float* vbase = v + ((size_t)(b * H_ + h) * S_) * DK_;

    msk[tid]       = pmask[b * S_ + tid];
    msk[tid + 256] = pmask[b * S_ + tid + 256];

    const int qrow = tid >> 3;            // 0..31
    const int sub  = tid & 7;             // 0..7
    const int qg   = q0 + qrow;
    const int ktmax = (q0 + 31) >> 6;     // inclusive

    // Q row held in registers (8 threads per row broadcast from L1)
    float4 qreg[16];
    #pragma unroll
    for (int i = 0; i < 16; ++i)
        qreg[i] = *(const float4*)&qbase[qrow * DK_ + i * 4];

    // ---- scores: sc[q][kg] = (q . k)*scale + bias, masked ----
    for (int kt = 0; kt <= ktmax; ++kt) {
        __syncthreads();
        for (int u = tid; u < 1024; u += 256) {
            int r = u >> 4, c4 = (u & 15) << 2;
            float4 t4 = *(const float4*)&kbase[(size_t)(kt * 64 + r) * DK_ + c4];
            ks[r][c4+0] = t4.x; ks[r][c4+1] = t4.y;
            ks[r][c4+2] = t4.z; ks[r][c4+3] = t4.w;
        }
        __syncthreads();
        #pragma unroll
        for (int kk8 = 0; kk8 < 8; ++kk8) {
            int kr = sub + kk8 * 8;
            int kg = kt * 64 + kr;
            float s = 0.f;
            #pragma unroll
            for (int i = 0; i < 16; ++i) {
                float4 k4 = *(const float4*)&ks[kr][i * 4];
                s = fmaf(qreg[i].x, k4.x, s);
                s = fmaf(qreg[i].y, k4.y, s);
                s = fmaf(qreg[i].z, k4.z, s);
                s = fmaf(qreg[i].w, k4.w, s);
            }
            s = fmaf(s, SCALE_, bias[((size_t)b * S_ + qg) * S_ + kg]);
            if (msk[kg] == 0 || kg > qg) s = -1e30f;
            sc[qrow][kg] = s;
        }
    }
    __syncthreads();

    // ---- softmax (8-lane group per row; threads read only own writes) ----
    const int kmax = (ktmax + 1) * 64;
    float mx = -1e30f;
    for (int kk = sub; kk < kmax; kk += 8) mx = fmaxf(mx, sc[qrow][kk]);
    mx = fmaxf(mx, __shfl_xor(mx, 1));
    mx = fmaxf(mx, __shfl_xor(mx, 2));
    mx = fmaxf(mx, __shfl_xor(mx, 4));
    float l = 0.f;
    for (int kk = sub; kk < kmax; kk += 8) {
        float p = __expf(sc[qrow][kk] - mx);
        sc[qrow][kk] = p;
        l += p;
    }
    l += __shfl_xor(l, 1);
    l += __shfl_xor(l, 2);
    l += __shfl_xor(l, 4);
    const float linv = 1.f / l;

    // ---- PV: out[qrow][d0..d0+8] = sum_k p * v, then normalize ----
    float out8[8] = {};
    const int d0 = sub * 8;
    for (int kt = 0; kt <= ktmax; ++kt) {
        __syncthreads();    // also orders softmax p-writes before first read
        for (int u = tid; u < 1024; u += 256) {
            int r = u >> 4, c4 = (u & 15) << 2;
            *(float4*)&vs[r][c4] =
                *(const float4*)&vbase[(size_t)(kt * 64 + r) * DK_ + c4];
        }
        __syncthreads();
        #pragma unroll 8
        for (int kk = 0; kk < 64; ++kk) {
            float p = sc[qrow][kt * 64 + kk];
            float4 va = *(const float4*)&vs[kk][d0];
            float4 vb = *(const float4*)&vs[kk][d0 + 4];
            out8[0] = fmaf(p, va.x, out8[0]);
            out8[1] = fmaf(p, va.y, out8[1]);
            out8[2] = fmaf(p, va.z, out8[2]);
            out8[3] = fmaf(p, va.w, out8[3]);
            out8[4] = fmaf(p, vb.x, out8[4]);
            out8[5] = fmaf(p, vb.y, out8[5]);
            out8[6] = fmaf(p, vb.z, out8[6]);
            out8[7] = fmaf(p, vb.w, out8[7]);
        }
    }

    float* obase = attn + ((size_t)(b * S_ + qg)) * D_ + h * DK_ + d0;
    float4 o1 = { out8[0] * linv, out8[1] * linv, out8[2] * linv, out8[3] * linv };
    float4 o2 = { out8[4] * linv, out8[5] * linv, out8[6] * linv, out8[7] * linv };
    *(float4*)&obase[0] = o1;
    *(float4*)&obase[4] = o2;
}

extern "C" void kernel_launch(void* const* d_in, const int* in_sizes, int n_in,
                              void* d_out, int out_size, void* d_ws, size_t ws_size,
                              hipStream_t stream)
{
    const float* x     = (const float*)d_in[0];
    const int*   pm    = (const int*)  d_in[1];
    const float* tm    = (const float*)d_in[2];
    const float* wq    = (const float*)d_in[3];
    const float* bq    = (const float*)d_in[4];
    const float* wk    = (const float*)d_in[5];
    const float* bk    = (const float*)d_in[6];
    const float* wv    = (const float*)d_in[7];
    const float* bv    = (const float*)d_in[8];
    const float* wp    = (const float*)d_in[9];
    const float* bp    = (const float*)d_in[10];
    const float* w_tb1 = (const float*)d_in[11];
    const float* b_tb1 = (const float*)d_in[12];
    const float* w_tb2 = (const float*)d_in[13];
    const float* b_tb2 = (const float*)d_in[14];

    float* ws = (float*)d_ws;
    float* qw = ws;                    // 4M floats (B,H,S,DK)
    float* kw = ws + 4194304;
    float* vw = ws + 8388608;
    float* bw = ws + 12582912;         // 2M floats (B,S,S)
    float* aw = ws + 14680064;         // 4M floats (B,S,D)

    dim3 gg(32, 16);
    gemm_kernel<1><<<gg, 256, 0, stream>>>(x, wq, bq, qw);
    gemm_kernel<1><<<gg, 256, 0, stream>>>(x, wk, bk, kw);
    gemm_kernel<1><<<gg, 256, 0, stream>>>(x, wv, bv, vw);
    tbias_kernel<<<2048, 256, 0, stream>>>(tm, w_tb1, b_tb1, w_tb2, b_tb2, bw);
    dim3 ga(16, H_, B_);
    attn_kernel<<<ga, 256, 0, stream>>>(qw, kw, vw, bw, pm, aw);
    gemm_kernel<0><<<gg, 256, 0, stream>>>(aw, wp, bp, (float*)d_out);
}

// Round 3
// 525.646 us; speedup vs baseline: 2.0640x; 2.0640x over previous
//
#include <hip/hip_runtime.h>
#include <hip/hip_bf16.h>

#define B_  8
#define S_  512
#define D_  1024
#define H_  16
#define DK_ 64
#define TB_ 64
#define SCALE_ 0.125f      // DK^-0.5

typedef __attribute__((ext_vector_type(8))) short          bh8;    // 8 bf16 (4 VGPR) MFMA frag
typedef __attribute__((ext_vector_type(4))) float          f32x4;  // MFMA acc
typedef __attribute__((ext_vector_type(8))) unsigned short us8;    // 16B bf16 store

// RNE fp32 -> bf16 (bit-level; no dependence on hip_bf16 struct layout)
__device__ __forceinline__ unsigned short f2bf(float f) {
    unsigned u = __float_as_uint(f);
    unsigned r = 0x7fffu + ((u >> 16) & 1u);
    return (unsigned short)((u + r) >> 16);
}

// ---------------------------------------------------------------------------
// fp32 -> bf16 flat convert (x: 4M elements)
// ---------------------------------------------------------------------------
__global__ __launch_bounds__(256)
void cvt_x_kernel(const float* __restrict__ in, unsigned short* __restrict__ out, int n8)
{
    int i = blockIdx.x * 256 + threadIdx.x;
    if (i >= n8) return;
    float4 a = *(const float4*)&in[(size_t)i * 8];
    float4 b = *(const float4*)&in[(size_t)i * 8 + 4];
    us8 o;
    o[0] = f2bf(a.x); o[1] = f2bf(a.y); o[2] = f2bf(a.z); o[3] = f2bf(a.w);
    o[4] = f2bf(b.x); o[5] = f2bf(b.y); o[6] = f2bf(b.z); o[7] = f2bf(b.w);
    *(us8*)&out[(size_t)i * 8] = o;
}

// ---------------------------------------------------------------------------
// Weight transpose+convert: Wt[n][k] = bf16(W[k][n])   (1024x1024)
// 64x64 LDS tile, conflict-free (65 stride)
// ---------------------------------------------------------------------------
__global__ __launch_bounds__(256)
void cvt_wt_kernel(const float* __restrict__ W, unsigned short* __restrict__ Wt)
{
    __shared__ float t[64][65];
    const int bx = blockIdx.x, by = blockIdx.y;
    const int c  = threadIdx.x & 63;
    const int r0 = threadIdx.x >> 6;          // 0..3
    #pragma unroll
    for (int i = 0; i < 16; ++i) {
        int r = r0 + i * 4;
        t[r][c] = W[(size_t)(by * 64 + r) * 1024 + bx * 64 + c];
    }
    __syncthreads();
    #pragma unroll
    for (int i = 0; i < 16; ++i) {
        int r = r0 + i * 4;
        Wt[(size_t)(bx * 64 + r) * 1024 + by * 64 + c] = f2bf(t[c][r]);
    }
}

// ---------------------------------------------------------------------------
// bf16 MFMA GEMM: C(4096x1024 f32) = A(4096x1024 bf16) @ Bt^T + bias
//   Bt is B-transposed: Bt[n][k].  BM=BN=128, BK=64, 4 waves (2x2), each wave
//   a 64x64 sub-tile = 4x4 frags of 16x16x32 MFMA.  m97-style 2-barrier loop.
// WRITE_QKV=1: scatter C to (B,H,S,DK).
// ---------------------------------------------------------------------------
template<int WRITE_QKV>
__global__ __launch_bounds__(256)
void gemm_bf16_kernel(const unsigned short* __restrict__ A,
                      const unsigned short* __restrict__ Bt,
                      const float* __restrict__ bias,
                      float* __restrict__ C)
{
    __shared__ unsigned short As[128][72];   // +16B pad: frag reads ~2-way max
    __shared__ unsigned short Bs[128][72];
    const int tid  = threadIdx.x;
    const int lane = tid & 63;
    const int wid  = tid >> 6;               // 0..3
    const int wr   = wid >> 1, wc = wid & 1; // 2x2 wave grid
    const int row0 = blockIdx.x * 128;
    const int col0 = blockIdx.y * 128;

    f32x4 acc[4][4] = {};

    const int ur = tid >> 3;                 // staging row (0..31, +32*i)
    const int uc = (tid & 7) * 8;            // staging col (elements)
    const int fr = lane & 15;                // frag row/col within 16
    const int fk = (lane >> 4) * 8;          // frag k-offset within 32

    for (int k0 = 0; k0 < 1024; k0 += 64) {
        __syncthreads();
        #pragma unroll
        for (int i = 0; i < 4; ++i) {
            int r = ur + i * 32;
            *(int4*)&As[r][uc] = *(const int4*)&A [(size_t)(row0 + r) * 1024 + k0 + uc];
            *(int4*)&Bs[r][uc] = *(const int4*)&Bt[(size_t)(col0 + r) * 1024 + k0 + uc];
        }
        __syncthreads();
        #pragma unroll
        for (int ks = 0; ks < 2; ++ks) {
            bh8 af[4], bfr[4];
            #pragma unroll
            for (int r = 0; r < 4; ++r)
                af[r]  = *(const bh8*)&As[wr * 64 + r * 16 + fr][ks * 32 + fk];
            #pragma unroll
            for (int c = 0; c < 4; ++c)
                bfr[c] = *(const bh8*)&Bs[wc * 64 + c * 16 + fr][ks * 32 + fk];
            #pragma unroll
            for (int r = 0; r < 4; ++r)
                #pragma unroll
                for (int c = 0; c < 4; ++c)
                    acc[r][c] = __builtin_amdgcn_mfma_f32_16x16x32_bf16(
                        af[r], bfr[c], acc[r][c], 0, 0, 0);
        }
    }

    // epilogue: D lane map col=lane&15, row=(lane>>4)*4+j  [m89-verified]
    #pragma unroll
    for (int r = 0; r < 4; ++r) {
        #pragma unroll
        for (int c = 0; c < 4; ++c) {
            int n = col0 + wc * 64 + c * 16 + (lane & 15);
            float bn = bias[n];
            #pragma unroll
            for (int j = 0; j < 4; ++j) {
                int m = row0 + wr * 64 + r * 16 + (lane >> 4) * 4 + j;
                float o = acc[r][c][j] + bn;
                if (WRITE_QKV) {
                    int bb = m >> 9, ss = m & 511;
                    int hh = n >> 6, dd = n & 63;
                    C[((size_t)((bb * H_ + hh) * S_ + ss)) * DK_ + dd] = o;
                } else {
                    C[(size_t)m * 1024 + n] = o;
                }
            }
        }
    }
}

// ---------------------------------------------------------------------------
// Temporal bias MLP (head-independent, computed once)
// ---------------------------------------------------------------------------
__global__ __launch_bounds__(256)
void tbias_kernel(const float* __restrict__ tm, const float* __restrict__ w1,
                  const float* __restrict__ b1, const float* __restrict__ w2,
                  const float* __restrict__ b2, float* __restrict__ bias)
{
    __shared__ float sw1[TB_], sb1[TB_], sw2[TB_];
    if (threadIdx.x < TB_) {
        sw1[threadIdx.x] = w1[threadIdx.x];
        sb1[threadIdx.x] = b1[threadIdx.x];
        sw2[threadIdx.x] = w2[threadIdx.x];
    }
    __syncthreads();
    const float ec  = 2.7182818284590452f;
    const float b2v = b2[0];
    const int n = B_ * S_ * S_;
    for (int i = blockIdx.x * blockDim.x + threadIdx.x; i < n;
         i += gridDim.x * blockDim.x) {
        float t   = 1.0f / logf(ec + tm[i]);
        float acc = b2v;
        #pragma unroll
        for (int j = 0; j < TB_; ++j) {
            float h = fmaf(t, sw1[j], sb1[j]);
            h = (h >= 0.f) ? h : 0.2f * h;
            acc = fmaf(h, sw2[j], acc);
        }
        bias[i] = acc;
    }
}

// ---------------------------------------------------------------------------
// Flash attention: block = (b, h, 32-q-tile), 256 threads.
// Online softmax; K and V share one LDS buffer; P tile in LDS.
// LDS = 17.4K (kv) + 8.7K (p) + 2K (msk) = 28.1 KB.
// Output written directly as bf16 (B,S,D) for the proj MFMA GEMM.
// ---------------------------------------------------------------------------
__global__ __launch_bounds__(256)
void attn_kernel(const float* __restrict__ q, const float* __restrict__ k,
                 const float* __restrict__ v, const float* __restrict__ bias,
                 const int* __restrict__ pmask, unsigned short* __restrict__ outb)
{
    __shared__ float kv[64][68];
    __shared__ float ps[32][68];
    __shared__ int   msk[S_];

    const int tid = threadIdx.x;
    const int qt  = blockIdx.x;          // 0..15
    const int h   = blockIdx.y;
    const int b   = blockIdx.z;
    const int q0  = qt * 32;

    const size_t hb    = (size_t)(b * H_ + h) * S_;
    const float* kbase = k + hb * DK_;
    const float* vbase = v + hb * DK_;

    msk[tid]       = pmask[b * S_ + tid];
    msk[tid + 256] = pmask[b * S_ + tid + 256];

    const int qrow = tid >> 3;           // 0..31
    const int sub  = tid & 7;            // 0..7
    const int qg   = q0 + qrow;
    const int d0   = sub * 8;
    const int ktmax = (q0 + 31) >> 6;

    const float* qptr = q + (hb + qg) * DK_;
    float4 qreg[16];
    #pragma unroll
    for (int i = 0; i < 16; ++i) qreg[i] = *(const float4*)&qptr[i * 4];

    const float* biasrow = bias + ((size_t)b * S_ + qg) * S_;

    float m_run = -1e30f, l_run = 0.f;
    float out8[8] = {};

    for (int kt = 0; kt <= ktmax; ++kt) {
        __syncthreads();                       // prev PV done with kv
        for (int u = tid; u < 1024; u += 256) {
            int r = u >> 4, c4 = (u & 15) << 2;
            *(float4*)&kv[r][c4] =
                *(const float4*)&kbase[(size_t)(kt * 64 + r) * DK_ + c4];
        }
        __syncthreads();

        // --- scores (8 per thread, k = kt*64 + j*8 + sub) ---
        float s[8];
        #pragma unroll
        for (int j = 0; j < 8; ++j) {
            int kr = j * 8 + sub;
            int kg = kt * 64 + kr;
            float a = 0.f;
            #pragma unroll
            for (int i = 0; i < 16; ++i) {
                float4 k4 = *(const float4*)&kv[kr][i * 4];
                a = fmaf(qreg[i].x, k4.x, a);
                a = fmaf(qreg[i].y, k4.y, a);
                a = fmaf(qreg[i].z, k4.z, a);
                a = fmaf(qreg[i].w, k4.w, a);
            }
            a = fmaf(a, SCALE_, biasrow[kg]);
            if (msk[kg] == 0 || kg > qg) a = -1e30f;
            s[j] = a;
        }

        // --- online softmax update (8-lane row groups) ---
        float mt = s[0];
        #pragma unroll
        for (int j = 1; j < 8; ++j) mt = fmaxf(mt, s[j]);
        mt = fmaxf(mt, __shfl_xor(mt, 1));
        mt = fmaxf(mt, __shfl_xor(mt, 2));
        mt = fmaxf(mt, __shfl_xor(mt, 4));
        float m_new = fmaxf(m_run, mt);
        float resc  = __expf(m_run - m_new);
        float psum  = 0.f;
        #pragma unroll
        for (int j = 0; j < 8; ++j) {
            float p = (s[j] < -1e29f) ? 0.f : __expf(s[j] - m_new);
            ps[qrow][j * 8 + sub] = p;
            psum += p;
        }
        psum += __shfl_xor(psum, 1);
        psum += __shfl_xor(psum, 2);
        psum += __shfl_xor(psum, 4);
        l_run = l_run * resc + psum;
        m_run = m_new;
        #pragma unroll
        for (int d = 0; d < 8; ++d) out8[d] *= resc;

        __syncthreads();                       // K reads + p writes done
        for (int u = tid; u < 1024; u += 256) {
            int r = u >> 4, c4 = (u & 15) << 2;
            *(float4*)&kv[r][c4] =
                *(const float4*)&vbase[(size_t)(kt * 64 + r) * DK_ + c4];
        }
        __syncthreads();

        // --- PV ---
        #pragma unroll 8
        for (int kk = 0; kk < 64; ++kk) {
            float p = ps[qrow][kk];
            float4 va = *(const float4*)&kv[kk][d0];
            float4 vb = *(const float4*)&kv[kk][d0 + 4];
            out8[0] = fmaf(p, va.x, out8[0]);
            out8[1] = fmaf(p, va.y, out8[1]);
            out8[2] = fmaf(p, va.z, out8[2]);
            out8[3] = fmaf(p, va.w, out8[3]);
            out8[4] = fmaf(p, vb.x, out8[4]);
            out8[5] = fmaf(p, vb.y, out8[5]);
            out8[6] = fmaf(p, vb.z, out8[6]);
            out8[7] = fmaf(p, vb.w, out8[7]);
        }
    }

    const float linv = 1.f / l_run;
    us8 o;
    #pragma unroll
    for (int d = 0; d < 8; ++d) o[d] = f2bf(out8[d] * linv);
    *(us8*)&outb[((size_t)(b * S_ + qg)) * D_ + h * DK_ + d0] = o;
}

extern "C" void kernel_launch(void* const* d_in, const int* in_sizes, int n_in,
                              void* d_out, int out_size, void* d_ws, size_t ws_size,
                              hipStream_t stream)
{
    const float* x     = (const float*)d_in[0];
    const int*   pm    = (const int*)  d_in[1];
    const float* tm    = (const float*)d_in[2];
    const float* wq    = (const float*)d_in[3];
    const float* bq    = (const float*)d_in[4];
    const float* wk    = (const float*)d_in[5];
    const float* bk    = (const float*)d_in[6];
    const float* wv    = (const float*)d_in[7];
    const float* bv    = (const float*)d_in[8];
    const float* wp    = (const float*)d_in[9];
    const float* bp    = (const float*)d_in[10];
    const float* w_tb1 = (const float*)d_in[11];
    const float* b_tb1 = (const float*)d_in[12];
    const float* w_tb2 = (const float*)d_in[13];
    const float* b_tb2 = (const float*)d_in[14];

    char* wsb = (char*)d_ws;
    const size_t MB = 1u << 20;
    unsigned short* xb  = (unsigned short*)wsb;             // 8MB, reused as awb
    unsigned short* wtq = (unsigned short*)(wsb + 8  * MB); // 2MB each
    unsigned short* wtk = wtq + 1048576;
    unsigned short* wtv = wtk + 1048576;
    unsigned short* wtp = wtv + 1048576;
    float* qw = (float*)(wsb + 16 * MB);                    // 16MB
    float* kw = (float*)(wsb + 32 * MB);
    float* vw = (float*)(wsb + 48 * MB);
    float* bw = (float*)(wsb + 64 * MB);                    // 8MB -> 72MB total

    cvt_x_kernel<<<2048, 256, 0, stream>>>(x, xb, 524288);
    dim3 gw(16, 16);
    cvt_wt_kernel<<<gw, 256, 0, stream>>>(wq, wtq);
    cvt_wt_kernel<<<gw, 256, 0, stream>>>(wk, wtk);
    cvt_wt_kernel<<<gw, 256, 0, stream>>>(wv, wtv);
    cvt_wt_kernel<<<gw, 256, 0, stream>>>(wp, wtp);

    dim3 gg(32, 8);
    gemm_bf16_kernel<1><<<gg, 256, 0, stream>>>(xb, wtq, bq, qw);
    gemm_bf16_kernel<1><<<gg, 256, 0, stream>>>(xb, wtk, bk, kw);
    gemm_bf16_kernel<1><<<gg, 256, 0, stream>>>(xb, wtv, bv, vw);

    tbias_kernel<<<2048, 256, 0, stream>>>(tm, w_tb1, b_tb1, w_tb2, b_tb2, bw);

    dim3 ga(16, H_, B_);
    attn_kernel<<<ga, 256, 0, stream>>>(qw, kw, vw, bw, pm, xb /*awb*/);

    gemm_bf16_kernel<0><<<gg, 256, 0, stream>>>(xb, wtp, bp, (float*)d_out);
}

// Round 4
// 262.853 us; speedup vs baseline: 4.1275x; 1.9998x over previous
//
#include <hip/hip_runtime.h>
#include <hip/hip_bf16.h>

#define B_  8
#define S_  512
#define D_  1024
#define H_  16
#define DK_ 64
#define TB_ 64
#define SCALE_ 0.125f      // DK^-0.5

typedef __attribute__((ext_vector_type(8))) short          bh8;    // 8 bf16 MFMA frag
typedef __attribute__((ext_vector_type(4))) float          f32x4;  // MFMA acc
typedef __attribute__((ext_vector_type(8))) unsigned short us8;    // 16B bf16 store

__device__ __forceinline__ unsigned short f2bf(float f) {
    unsigned u = __float_as_uint(f);
    unsigned r = 0x7fffu + ((u >> 16) & 1u);
    return (unsigned short)((u + r) >> 16);
}

// ---------------------------------------------------------------------------
// fp32 -> bf16 flat convert (x: 4M elements)
// ---------------------------------------------------------------------------
__global__ __launch_bounds__(256)
void cvt_x_kernel(const float* __restrict__ in, unsigned short* __restrict__ out, int n8)
{
    int i = blockIdx.x * 256 + threadIdx.x;
    if (i >= n8) return;
    float4 a = *(const float4*)&in[(size_t)i * 8];
    float4 b = *(const float4*)&in[(size_t)i * 8 + 4];
    us8 o;
    o[0] = f2bf(a.x); o[1] = f2bf(a.y); o[2] = f2bf(a.z); o[3] = f2bf(a.w);
    o[4] = f2bf(b.x); o[5] = f2bf(b.y); o[6] = f2bf(b.z); o[7] = f2bf(b.w);
    *(us8*)&out[(size_t)i * 8] = o;
}

// ---------------------------------------------------------------------------
// Weight transpose+convert: Wt[n][k] = bf16(W[k][n])   (1024x1024)
// ---------------------------------------------------------------------------
__global__ __launch_bounds__(256)
void cvt_wt_kernel(const float* __restrict__ W, unsigned short* __restrict__ Wt)
{
    __shared__ float t[64][65];
    const int bx = blockIdx.x, by = blockIdx.y;
    const int c  = threadIdx.x & 63;
    const int r0 = threadIdx.x >> 6;
    #pragma unroll
    for (int i = 0; i < 16; ++i) {
        int r = r0 + i * 4;
        t[r][c] = W[(size_t)(by * 64 + r) * 1024 + bx * 64 + c];
    }
    __syncthreads();
    #pragma unroll
    for (int i = 0; i < 16; ++i) {
        int r = r0 + i * 4;
        Wt[(size_t)(bx * 64 + r) * 1024 + by * 64 + c] = f2bf(t[c][r]);
    }
}

// ---------------------------------------------------------------------------
// bf16 MFMA GEMM: C(4096x1024) = A(4096x1024 bf16) @ Bt^T + bias
// MODE 0: f32 row-major out.  MODE 1: bf16 out scattered (B,H,S,DK).
// MODE 2: bf16 out scattered TRANSPOSED (B,H,DK,S)  (for V).
// ---------------------------------------------------------------------------
template<int MODE>
__global__ __launch_bounds__(256)
void gemm_bf16_kernel(const unsigned short* __restrict__ A,
                      const unsigned short* __restrict__ Bt,
                      const float* __restrict__ bias,
                      float* __restrict__ C, unsigned short* __restrict__ Cb)
{
    __shared__ unsigned short As[128][72];
    __shared__ unsigned short Bs[128][72];
    const int tid  = threadIdx.x;
    const int lane = tid & 63;
    const int wid  = tid >> 6;
    const int wr   = wid >> 1, wc = wid & 1;
    const int row0 = blockIdx.x * 128;
    const int col0 = blockIdx.y * 128;

    f32x4 acc[4][4] = {};

    const int ur = tid >> 3;
    const int uc = (tid & 7) * 8;
    const int fr = lane & 15;
    const int fk = (lane >> 4) * 8;

    for (int k0 = 0; k0 < 1024; k0 += 64) {
        __syncthreads();
        #pragma unroll
        for (int i = 0; i < 4; ++i) {
            int r = ur + i * 32;
            *(int4*)&As[r][uc] = *(const int4*)&A [(size_t)(row0 + r) * 1024 + k0 + uc];
            *(int4*)&Bs[r][uc] = *(const int4*)&Bt[(size_t)(col0 + r) * 1024 + k0 + uc];
        }
        __syncthreads();
        #pragma unroll
        for (int ks = 0; ks < 2; ++ks) {
            bh8 af[4], bfr[4];
            #pragma unroll
            for (int r = 0; r < 4; ++r)
                af[r]  = *(const bh8*)&As[wr * 64 + r * 16 + fr][ks * 32 + fk];
            #pragma unroll
            for (int c = 0; c < 4; ++c)
                bfr[c] = *(const bh8*)&Bs[wc * 64 + c * 16 + fr][ks * 32 + fk];
            #pragma unroll
            for (int r = 0; r < 4; ++r)
                #pragma unroll
                for (int c = 0; c < 4; ++c)
                    acc[r][c] = __builtin_amdgcn_mfma_f32_16x16x32_bf16(
                        af[r], bfr[c], acc[r][c], 0, 0, 0);
        }
    }

    #pragma unroll
    for (int r = 0; r < 4; ++r) {
        #pragma unroll
        for (int c = 0; c < 4; ++c) {
            int n = col0 + wc * 64 + c * 16 + (lane & 15);
            float bn = bias[n];
            #pragma unroll
            for (int j = 0; j < 4; ++j) {
                int m = row0 + wr * 64 + r * 16 + (lane >> 4) * 4 + j;
                float o = acc[r][c][j] + bn;
                if (MODE == 0) {
                    C[(size_t)m * 1024 + n] = o;
                } else {
                    int bb = m >> 9, ss = m & 511;
                    int hh = n >> 6, dd = n & 63;
                    if (MODE == 1)
                        Cb[((size_t)((bb * H_ + hh) * S_ + ss)) * DK_ + dd] = f2bf(o);
                    else
                        Cb[((size_t)((bb * H_ + hh) * DK_ + dd)) * S_ + ss] = f2bf(o);
                }
            }
        }
    }
}

// ---------------------------------------------------------------------------
// Temporal bias MLP, padding mask folded in (bias = -1e30 where masked)
// ---------------------------------------------------------------------------
__global__ __launch_bounds__(256)
void tbias_kernel(const float* __restrict__ tm, const int* __restrict__ pmask,
                  const float* __restrict__ w1, const float* __restrict__ b1,
                  const float* __restrict__ w2, const float* __restrict__ b2,
                  float* __restrict__ bias)
{
    __shared__ float sw1[TB_], sb1[TB_], sw2[TB_];
    if (threadIdx.x < TB_) {
        sw1[threadIdx.x] = w1[threadIdx.x];
        sb1[threadIdx.x] = b1[threadIdx.x];
        sw2[threadIdx.x] = w2[threadIdx.x];
    }
    __syncthreads();
    const float ec  = 2.7182818284590452f;
    const float b2v = b2[0];
    const int n = B_ * S_ * S_;
    for (int i = blockIdx.x * blockDim.x + threadIdx.x; i < n;
         i += gridDim.x * blockDim.x) {
        int bb = i >> 18;          // S*S = 2^18
        int jj = i & (S_ - 1);     // key index
        float t   = 1.0f / logf(ec + tm[i]);
        float acc = b2v;
        #pragma unroll
        for (int j = 0; j < TB_; ++j) {
            float h = fmaf(t, sw1[j], sb1[j]);
            h = (h >= 0.f) ? h : 0.2f * h;
            acc = fmaf(h, sw2[j], acc);
        }
        bias[i] = (pmask[bb * S_ + jj] == 0) ? -1e30f : acc;
    }
}

// ---------------------------------------------------------------------------
// MFMA flash attention. Block = (qt, h, b): 4 waves, QBLK=64 (16 q-rows/wave),
// KV tile 64. Causal: tiles 0..qt. Q frags in regs; K, Vt, P in LDS (stride
// 72 bf16 = 144B rows -> <=2-way conflicts on b128 frag reads).
// P is per-wave-private (16-row band): no barrier between P write and read,
// only lgkmcnt(0). Output bf16 (B,S,D).
// ---------------------------------------------------------------------------
__global__ __launch_bounds__(256)
void attn_kernel(const unsigned short* __restrict__ q,
                 const unsigned short* __restrict__ k,
                 const unsigned short* __restrict__ vt,
                 const float* __restrict__ biasm,
                 unsigned short* __restrict__ outb)
{
    __shared__ unsigned short Kl[64][72];
    __shared__ unsigned short Vl[64][72];
    __shared__ unsigned short Pl[64][72];

    const int tid  = threadIdx.x;
    const int lane = tid & 63;
    const int w    = tid >> 6;           // wave 0..3
    const int qt   = blockIdx.x;         // 0..7
    const int h    = blockIdx.y;
    const int b    = blockIdx.z;
    const int q0   = qt * 64;

    const int l15 = lane & 15;
    const int g   = lane >> 4;           // 0..3

    const size_t hb  = (size_t)(b * H_ + h) * S_;
    const unsigned short* kbase  = k  + hb * DK_;
    const unsigned short* vtbase = vt + ((size_t)(b * H_ + h) * DK_) * S_;

    // Q A-fragments (held across the whole KV loop)
    const int qrow_a = q0 + w * 16 + l15;
    bh8 aq0 = *(const bh8*)&q[(hb + qrow_a) * DK_ +      g * 8];
    bh8 aq1 = *(const bh8*)&q[(hb + qrow_a) * DK_ + 32 + g * 8];

    const int qd = q0 + w * 16 + g * 4;  // D-layout q base (+j)

    f32x4 acc_o[4] = {};
    float m_run[4] = { -1e30f, -1e30f, -1e30f, -1e30f };
    float l_run[4] = {};

    for (int kt = 0; kt <= qt; ++kt) {
        __syncthreads();                 // prior tile's LDS reads complete
        #pragma unroll
        for (int s = 0; s < 2; ++s) {
            int u  = tid + s * 256;      // 512 int4 units per 64x64 tile
            int r  = u >> 3;
            int c8 = (u & 7) * 8;
            *(int4*)&Kl[r][c8] = *(const int4*)&kbase [(size_t)(kt * 64 + r) * DK_ + c8];
            *(int4*)&Vl[r][c8] = *(const int4*)&vtbase[(size_t)r * S_ + kt * 64 + c8];
        }
        __syncthreads();

        // ---- QK^T: S[q][kk], 4 col-tiles x K=64 ----
        f32x4 sc[4];
        #pragma unroll
        for (int c = 0; c < 4; ++c) {
            bh8 bk0 = *(const bh8*)&Kl[c * 16 + l15][     g * 8];
            bh8 bk1 = *(const bh8*)&Kl[c * 16 + l15][32 + g * 8];
            f32x4 z = {};
            z = __builtin_amdgcn_mfma_f32_16x16x32_bf16(aq0, bk0, z, 0, 0, 0);
            sc[c] = __builtin_amdgcn_mfma_f32_16x16x32_bf16(aq1, bk1, z, 0, 0, 0);
        }

        // ---- scale + bias(+pad mask) + causal; online softmax per q-row j ----
        float sv[4][4];                  // [c][j]
        #pragma unroll
        for (int j = 0; j < 4; ++j) {
            const float* br = biasm + ((size_t)b * S_ + qd + j) * S_ + kt * 64;
            #pragma unroll
            for (int c = 0; c < 4; ++c)
                sv[c][j] = fmaf(sc[c][j], SCALE_, br[c * 16 + l15]);
        }
        if (kt == qt) {                  // diagonal tile: causal mask
            #pragma unroll
            for (int c = 0; c < 4; ++c) {
                int kloc = c * 16 + l15;
                #pragma unroll
                for (int j = 0; j < 4; ++j)
                    if (kloc > w * 16 + g * 4 + j) sv[c][j] = -1e30f;
            }
        }

        #pragma unroll
        for (int j = 0; j < 4; ++j) {
            float mt = fmaxf(fmaxf(sv[0][j], sv[1][j]), fmaxf(sv[2][j], sv[3][j]));
            mt = fmaxf(mt, __shfl_xor(mt, 1));
            mt = fmaxf(mt, __shfl_xor(mt, 2));
            mt = fmaxf(mt, __shfl_xor(mt, 4));
            mt = fmaxf(mt, __shfl_xor(mt, 8));
            float m_new = fmaxf(m_run[j], mt);
            float resc  = __expf(m_run[j] - m_new);
            float psum  = 0.f;
            #pragma unroll
            for (int c = 0; c < 4; ++c) {
                float p = __expf(sv[c][j] - m_new);
                Pl[w * 16 + g * 4 + j][c * 16 + l15] = f2bf(p);
                psum += p;
            }
            psum += __shfl_xor(psum, 1);
            psum += __shfl_xor(psum, 2);
            psum += __shfl_xor(psum, 4);
            psum += __shfl_xor(psum, 8);
            l_run[j] = l_run[j] * resc + psum;
            m_run[j] = m_new;
            acc_o[0][j] *= resc; acc_o[1][j] *= resc;
            acc_o[2][j] *= resc; acc_o[3][j] *= resc;
        }

        // drain own wave's P writes (P band is wave-private; no barrier)
        asm volatile("s_waitcnt lgkmcnt(0)" ::: "memory");

        // ---- PV: O += P(16x64) @ V(64x64) ----
        bh8 ap0 = *(const bh8*)&Pl[w * 16 + l15][     g * 8];
        bh8 ap1 = *(const bh8*)&Pl[w * 16 + l15][32 + g * 8];
        #pragma unroll
        for (int c2 = 0; c2 < 4; ++c2) {
            bh8 bv0 = *(const bh8*)&Vl[c2 * 16 + l15][     g * 8];
            bh8 bv1 = *(const bh8*)&Vl[c2 * 16 + l15][32 + g * 8];
            acc_o[c2] = __builtin_amdgcn_mfma_f32_16x16x32_bf16(ap0, bv0, acc_o[c2], 0, 0, 0);
            acc_o[c2] = __builtin_amdgcn_mfma_f32_16x16x32_bf16(ap1, bv1, acc_o[c2], 0, 0, 0);
        }
    }

    // ---- epilogue: normalize, write bf16 (B,S,D) ----
    #pragma unroll
    for (int j = 0; j < 4; ++j) {
        float linv = 1.f / l_run[j];
        #pragma unroll
        for (int c2 = 0; c2 < 4; ++c2)
            outb[((size_t)(b * S_ + qd + j)) * D_ + h * DK_ + c2 * 16 + l15] =
                f2bf(acc_o[c2][j] * linv);
    }
}

extern "C" void kernel_launch(void* const* d_in, const int* in_sizes, int n_in,
                              void* d_out, int out_size, void* d_ws, size_t ws_size,
                              hipStream_t stream)
{
    const float* x     = (const float*)d_in[0];
    const int*   pm    = (const int*)  d_in[1];
    const float* tm    = (const float*)d_in[2];
    const float* wq    = (const float*)d_in[3];
    const float* bq    = (const float*)d_in[4];
    const float* wk    = (const float*)d_in[5];
    const float* bk    = (const float*)d_in[6];
    const float* wv    = (const float*)d_in[7];
    const float* bv    = (const float*)d_in[8];
    const float* wp    = (const float*)d_in[9];
    const float* bp    = (const float*)d_in[10];
    const float* w_tb1 = (const float*)d_in[11];
    const float* b_tb1 = (const float*)d_in[12];
    const float* w_tb2 = (const float*)d_in[13];
    const float* b_tb2 = (const float*)d_in[14];

    char* wsb = (char*)d_ws;
    const size_t MB = 1u << 20;
    unsigned short* xb  = (unsigned short*)wsb;             // 8MB; reused for attn out
    unsigned short* wtq = (unsigned short*)(wsb + 8  * MB); // 2MB each
    unsigned short* wtk = wtq + 1048576;
    unsigned short* wtv = wtk + 1048576;
    unsigned short* wtp = wtv + 1048576;
    unsigned short* qw  = (unsigned short*)(wsb + 16 * MB); // 8MB bf16 (B,H,S,DK)
    unsigned short* kw  = (unsigned short*)(wsb + 24 * MB); // 8MB bf16 (B,H,S,DK)
    unsigned short* vtw = (unsigned short*)(wsb + 32 * MB); // 8MB bf16 (B,H,DK,S)
    float*          bw  = (float*)        (wsb + 40 * MB);  // 8MB f32 (B,S,S)

    cvt_x_kernel<<<2048, 256, 0, stream>>>(x, xb, 524288);
    dim3 gw(16, 16);
    cvt_wt_kernel<<<gw, 256, 0, stream>>>(wq, wtq);
    cvt_wt_kernel<<<gw, 256, 0, stream>>>(wk, wtk);
    cvt_wt_kernel<<<gw, 256, 0, stream>>>(wv, wtv);
    cvt_wt_kernel<<<gw, 256, 0, stream>>>(wp, wtp);

    dim3 gg(32, 8);
    gemm_bf16_kernel<1><<<gg, 256, 0, stream>>>(xb, wtq, bq, nullptr, qw);
    gemm_bf16_kernel<1><<<gg, 256, 0, stream>>>(xb, wtk, bk, nullptr, kw);
    gemm_bf16_kernel<2><<<gg, 256, 0, stream>>>(xb, wtv, bv, nullptr, vtw);

    tbias_kernel<<<2048, 256, 0, stream>>>(tm, pm, w_tb1, b_tb1, w_tb2, b_tb2, bw);

    dim3 ga(8, H_, B_);
    attn_kernel<<<ga, 256, 0, stream>>>(qw, kw, vtw, bw, xb /*out*/);

    gemm_bf16_kernel<0><<<gg, 256, 0, stream>>>(xb, wtp, bp, (float*)d_out, nullptr);
}

// Round 5
// 229.106 us; speedup vs baseline: 4.7355x; 1.1473x over previous
//
#include <hip/hip_runtime.h>
#include <hip/hip_bf16.h>

#define B_  8
#define S_  512
#define D_  1024
#define H_  16
#define DK_ 64
#define TB_ 64
#define SCALE_ 0.125f      // DK^-0.5

typedef __attribute__((ext_vector_type(8))) short          bh8;    // 8 bf16 MFMA frag
typedef __attribute__((ext_vector_type(4))) float          f32x4;  // MFMA acc
typedef __attribute__((ext_vector_type(8))) unsigned short us8;    // 16B bf16 store

__device__ __forceinline__ unsigned short f2bf(float f) {
    unsigned u = __float_as_uint(f);
    unsigned r = 0x7fffu + ((u >> 16) & 1u);
    return (unsigned short)((u + r) >> 16);
}

// ---------------------------------------------------------------------------
// fp32 -> bf16 flat convert (x: 4M elements)
// ---------------------------------------------------------------------------
__global__ __launch_bounds__(256)
void cvt_x_kernel(const float* __restrict__ in, unsigned short* __restrict__ out, int n8)
{
    int i = blockIdx.x * 256 + threadIdx.x;
    if (i >= n8) return;
    float4 a = *(const float4*)&in[(size_t)i * 8];
    float4 b = *(const float4*)&in[(size_t)i * 8 + 4];
    us8 o;
    o[0] = f2bf(a.x); o[1] = f2bf(a.y); o[2] = f2bf(a.z); o[3] = f2bf(a.w);
    o[4] = f2bf(b.x); o[5] = f2bf(b.y); o[6] = f2bf(b.z); o[7] = f2bf(b.w);
    *(us8*)&out[(size_t)i * 8] = o;
}

// ---------------------------------------------------------------------------
// Weight transpose+convert: Wt[n][k] = bf16(W[k][n])   (1024x1024)
// ---------------------------------------------------------------------------
__global__ __launch_bounds__(256)
void cvt_wt_kernel(const float* __restrict__ W, unsigned short* __restrict__ Wt)
{
    __shared__ float t[64][65];
    const int bx = blockIdx.x, by = blockIdx.y;
    const int c  = threadIdx.x & 63;
    const int r0 = threadIdx.x >> 6;
    #pragma unroll
    for (int i = 0; i < 16; ++i) {
        int r = r0 + i * 4;
        t[r][c] = W[(size_t)(by * 64 + r) * 1024 + bx * 64 + c];
    }
    __syncthreads();
    #pragma unroll
    for (int i = 0; i < 16; ++i) {
        int r = r0 + i * 4;
        Wt[(size_t)(bx * 64 + r) * 1024 + by * 64 + c] = f2bf(t[c][r]);
    }
}

// ---------------------------------------------------------------------------
// Fused QKV GEMM: [Q|K|V](4096x3072) = A(4096x1024 bf16) @ Wqkv_t^T + bias
// BM=128, BN=64, BK=64, 4 waves (2x2), wave tile 64x32 (4x2 frags).
// Grid (32,48) = 1536 blocks -> ~5-6 blocks/CU (vs 1 in prior round).
// Q,K -> (B,H,S,DK) bf16;  V -> (B,H,DK,S) bf16 (transposed for PV B-frags).
// ---------------------------------------------------------------------------
__global__ __launch_bounds__(256)
void gemm_qkv_kernel(const unsigned short* __restrict__ A,
                     const unsigned short* __restrict__ Wt,   // 3072x1024
                     const float* __restrict__ bq, const float* __restrict__ bk,
                     const float* __restrict__ bv,
                     unsigned short* __restrict__ qo,
                     unsigned short* __restrict__ ko,
                     unsigned short* __restrict__ vo)
{
    __shared__ unsigned short As[128][72];
    __shared__ unsigned short Bs[64][72];
    const int tid  = threadIdx.x;
    const int lane = tid & 63;
    const int wid  = tid >> 6;
    const int wr   = wid >> 1, wc = wid & 1;
    const int row0 = blockIdx.x * 128;
    const int col0 = blockIdx.y * 64;

    f32x4 acc[4][2] = {};

    const int ur = tid >> 3;           // 0..31
    const int uc = (tid & 7) * 8;
    const int fr = lane & 15;
    const int fk = (lane >> 4) * 8;
    const int g  = lane >> 4;

    for (int k0 = 0; k0 < 1024; k0 += 64) {
        __syncthreads();
        #pragma unroll
        for (int i = 0; i < 4; ++i) {
            int r = ur + i * 32;
            *(int4*)&As[r][uc] = *(const int4*)&A[(size_t)(row0 + r) * 1024 + k0 + uc];
        }
        #pragma unroll
        for (int i = 0; i < 2; ++i) {
            int r = ur + i * 32;
            *(int4*)&Bs[r][uc] = *(const int4*)&Wt[(size_t)(col0 + r) * 1024 + k0 + uc];
        }
        __syncthreads();
        #pragma unroll
        for (int ks = 0; ks < 2; ++ks) {
            bh8 af[4], bfr[2];
            #pragma unroll
            for (int r = 0; r < 4; ++r)
                af[r]  = *(const bh8*)&As[wr * 64 + r * 16 + fr][ks * 32 + fk];
            #pragma unroll
            for (int c = 0; c < 2; ++c)
                bfr[c] = *(const bh8*)&Bs[wc * 32 + c * 16 + fr][ks * 32 + fk];
            #pragma unroll
            for (int r = 0; r < 4; ++r)
                #pragma unroll
                for (int c = 0; c < 2; ++c)
                    acc[r][c] = __builtin_amdgcn_mfma_f32_16x16x32_bf16(
                        af[r], bfr[c], acc[r][c], 0, 0, 0);
        }
    }

    const int nh = col0 >> 10;                 // 0=Q 1=K 2=V (block-uniform)
    const float* bsel = (nh == 0) ? bq : (nh == 1) ? bk : bv;
    unsigned short* outp = (nh == 0) ? qo : (nh == 1) ? ko : vo;

    #pragma unroll
    for (int r = 0; r < 4; ++r) {
        #pragma unroll
        for (int c = 0; c < 2; ++c) {
            int n  = col0 + wc * 32 + c * 16 + (lane & 15);
            int nn = n & 1023;
            float bn = bsel[nn];
            int hh = nn >> 6, dd = nn & 63;
            #pragma unroll
            for (int j = 0; j < 4; ++j) {
                int m = row0 + wr * 64 + r * 16 + g * 4 + j;
                float o = acc[r][c][j] + bn;
                int bb = m >> 9, ss = m & 511;
                if (nh == 2)
                    outp[((size_t)((bb * H_ + hh) * DK_ + dd)) * S_ + ss] = f2bf(o);
                else
                    outp[((size_t)((bb * H_ + hh) * S_ + ss)) * DK_ + dd] = f2bf(o);
            }
        }
    }
}

// ---------------------------------------------------------------------------
// Proj GEMM: C(4096x1024 f32) = A(4096x1024 bf16) @ Wt^T + bias
// Same 128x64 tile; grid (32,16) = 512 blocks.
// ---------------------------------------------------------------------------
__global__ __launch_bounds__(256)
void gemm_proj_kernel(const unsigned short* __restrict__ A,
                      const unsigned short* __restrict__ Wt,
                      const float* __restrict__ bias,
                      float* __restrict__ C)
{
    __shared__ unsigned short As[128][72];
    __shared__ unsigned short Bs[64][72];
    const int tid  = threadIdx.x;
    const int lane = tid & 63;
    const int wid  = tid >> 6;
    const int wr   = wid >> 1, wc = wid & 1;
    const int row0 = blockIdx.x * 128;
    const int col0 = blockIdx.y * 64;

    f32x4 acc[4][2] = {};

    const int ur = tid >> 3;
    const int uc = (tid & 7) * 8;
    const int fr = lane & 15;
    const int fk = (lane >> 4) * 8;
    const int g  = lane >> 4;

    for (int k0 = 0; k0 < 1024; k0 += 64) {
        __syncthreads();
        #pragma unroll
        for (int i = 0; i < 4; ++i) {
            int r = ur + i * 32;
            *(int4*)&As[r][uc] = *(const int4*)&A[(size_t)(row0 + r) * 1024 + k0 + uc];
        }
        #pragma unroll
        for (int i = 0; i < 2; ++i) {
            int r = ur + i * 32;
            *(int4*)&Bs[r][uc] = *(const int4*)&Wt[(size_t)(col0 + r) * 1024 + k0 + uc];
        }
        __syncthreads();
        #pragma unroll
        for (int ks = 0; ks < 2; ++ks) {
            bh8 af[4], bfr[2];
            #pragma unroll
            for (int r = 0; r < 4; ++r)
                af[r]  = *(const bh8*)&As[wr * 64 + r * 16 + fr][ks * 32 + fk];
            #pragma unroll
            for (int c = 0; c < 2; ++c)
                bfr[c] = *(const bh8*)&Bs[wc * 32 + c * 16 + fr][ks * 32 + fk];
            #pragma unroll
            for (int r = 0; r < 4; ++r)
                #pragma unroll
                for (int c = 0; c < 2; ++c)
                    acc[r][c] = __builtin_amdgcn_mfma_f32_16x16x32_bf16(
                        af[r], bfr[c], acc[r][c], 0, 0, 0);
        }
    }

    #pragma unroll
    for (int r = 0; r < 4; ++r) {
        #pragma unroll
        for (int c = 0; c < 2; ++c) {
            int n = col0 + wc * 32 + c * 16 + (lane & 15);
            float bn = bias[n];
            #pragma unroll
            for (int j = 0; j < 4; ++j) {
                int m = row0 + wr * 64 + r * 16 + g * 4 + j;
                C[(size_t)m * 1024 + n] = acc[r][c][j] + bn;
            }
        }
    }
}

// ---------------------------------------------------------------------------
// Temporal bias MLP, padding mask folded in (bias = -1e30 where masked)
// ---------------------------------------------------------------------------
__global__ __launch_bounds__(256)
void tbias_kernel(const float* __restrict__ tm, const int* __restrict__ pmask,
                  const float* __restrict__ w1, const float* __restrict__ b1,
                  const float* __restrict__ w2, const float* __restrict__ b2,
                  float* __restrict__ bias)
{
    __shared__ float sw1[TB_], sb1[TB_], sw2[TB_];
    if (threadIdx.x < TB_) {
        sw1[threadIdx.x] = w1[threadIdx.x];
        sb1[threadIdx.x] = b1[threadIdx.x];
        sw2[threadIdx.x] = w2[threadIdx.x];
    }
    __syncthreads();
    const float ec  = 2.7182818284590452f;
    const float b2v = b2[0];
    const int n = B_ * S_ * S_;
    for (int i = blockIdx.x * blockDim.x + threadIdx.x; i < n;
         i += gridDim.x * blockDim.x) {
        int bb = i >> 18;
        int jj = i & (S_ - 1);
        float t   = 1.0f / logf(ec + tm[i]);
        float acc = b2v;
        #pragma unroll
        for (int j = 0; j < TB_; ++j) {
            float h = fmaf(t, sw1[j], sb1[j]);
            h = (h >= 0.f) ? h : 0.2f * h;
            acc = fmaf(h, sw2[j], acc);
        }
        bias[i] = (pmask[bb * S_ + jj] == 0) ? -1e30f : acc;
    }
}

// ---------------------------------------------------------------------------
// MFMA flash attention. 1D grid 1024 with XCD swizzle: each XCD gets one
// batch b; all 16 heads of a (b,qt) group run adjacently -> bias/K/V tile
// reads become per-XCD-L2 hits (working set ~4MB = L2 size).
// 4 waves, QBLK=64 (16 q-rows/wave), KV tile 64. Q frags in regs; K, Vt, P
// in LDS (stride 72 -> <=2-way conflicts). P band wave-private (lgkmcnt only).
// ---------------------------------------------------------------------------
__global__ __launch_bounds__(256)
void attn_kernel(const unsigned short* __restrict__ q,
                 const unsigned short* __restrict__ k,
                 const unsigned short* __restrict__ vt,
                 const float* __restrict__ biasm,
                 unsigned short* __restrict__ outb)
{
    __shared__ unsigned short Kl[64][72];
    __shared__ unsigned short Vl[64][72];
    __shared__ unsigned short Pl[64][72];

    const int tid  = threadIdx.x;
    const int lane = tid & 63;
    const int w    = tid >> 6;
    // XCD-aware swizzle (nwg=1024, 8 XCDs, bijective): XCD x runs lin in
    // [x*128, (x+1)*128) -> lin = b*128 + qt*16 + h  => one b per XCD.
    const int lin = (blockIdx.x & 7) * 128 + (blockIdx.x >> 3);
    const int h   = lin & 15;
    const int qt  = (lin >> 4) & 7;
    const int b   = lin >> 7;
    const int q0  = qt * 64;

    const int l15 = lane & 15;
    const int g   = lane >> 4;

    const size_t hb  = (size_t)(b * H_ + h) * S_;
    const unsigned short* kbase  = k  + hb * DK_;
    const unsigned short* vtbase = vt + ((size_t)(b * H_ + h) * DK_) * S_;

    const int qrow_a = q0 + w * 16 + l15;
    bh8 aq0 = *(const bh8*)&q[(hb + qrow_a) * DK_ +      g * 8];
    bh8 aq1 = *(const bh8*)&q[(hb + qrow_a) * DK_ + 32 + g * 8];

    const int qd = q0 + w * 16 + g * 4;

    f32x4 acc_o[4] = {};
    float m_run[4] = { -1e30f, -1e30f, -1e30f, -1e30f };
    float l_run[4] = {};

    for (int kt = 0; kt <= qt; ++kt) {
        __syncthreads();
        #pragma unroll
        for (int s = 0; s < 2; ++s) {
            int u  = tid + s * 256;
            int r  = u >> 3;
            int c8 = (u & 7) * 8;
            *(int4*)&Kl[r][c8] = *(const int4*)&kbase [(size_t)(kt * 64 + r) * DK_ + c8];
            *(int4*)&Vl[r][c8] = *(const int4*)&vtbase[(size_t)r * S_ + kt * 64 + c8];
        }
        __syncthreads();

        f32x4 sc[4];
        #pragma unroll
        for (int c = 0; c < 4; ++c) {
            bh8 bk0 = *(const bh8*)&Kl[c * 16 + l15][     g * 8];
            bh8 bk1 = *(const bh8*)&Kl[c * 16 + l15][32 + g * 8];
            f32x4 z = {};
            z = __builtin_amdgcn_mfma_f32_16x16x32_bf16(aq0, bk0, z, 0, 0, 0);
            sc[c] = __builtin_amdgcn_mfma_f32_16x16x32_bf16(aq1, bk1, z, 0, 0, 0);
        }

        float sv[4][4];
        #pragma unroll
        for (int j = 0; j < 4; ++j) {
            const float* br = biasm + ((size_t)b * S_ + qd + j) * S_ + kt * 64;
            #pragma unroll
            for (int c = 0; c < 4; ++c)
                sv[c][j] = fmaf(sc[c][j], SCALE_, br[c * 16 + l15]);
        }
        if (kt == qt) {
            #pragma unroll
            for (int c = 0; c < 4; ++c) {
                int kloc = c * 16 + l15;
                #pragma unroll
                for (int j = 0; j < 4; ++j)
                    if (kloc > w * 16 + g * 4 + j) sv[c][j] = -1e30f;
            }
        }

        #pragma unroll
        for (int j = 0; j < 4; ++j) {
            float mt = fmaxf(fmaxf(sv[0][j], sv[1][j]), fmaxf(sv[2][j], sv[3][j]));
            mt = fmaxf(mt, __shfl_xor(mt, 1));
            mt = fmaxf(mt, __shfl_xor(mt, 2));
            mt = fmaxf(mt, __shfl_xor(mt, 4));
            mt = fmaxf(mt, __shfl_xor(mt, 8));
            float m_new = fmaxf(m_run[j], mt);
            float resc  = __expf(m_run[j] - m_new);
            float psum  = 0.f;
            #pragma unroll
            for (int c = 0; c < 4; ++c) {
                float p = __expf(sv[c][j] - m_new);
                Pl[w * 16 + g * 4 + j][c * 16 + l15] = f2bf(p);
                psum += p;
            }
            psum += __shfl_xor(psum, 1);
            psum += __shfl_xor(psum, 2);
            psum += __shfl_xor(psum, 4);
            psum += __shfl_xor(psum, 8);
            l_run[j] = l_run[j] * resc + psum;
            m_run[j] = m_new;
            acc_o[0][j] *= resc; acc_o[1][j] *= resc;
            acc_o[2][j] *= resc; acc_o[3][j] *= resc;
        }

        asm volatile("s_waitcnt lgkmcnt(0)" ::: "memory");

        bh8 ap0 = *(const bh8*)&Pl[w * 16 + l15][     g * 8];
        bh8 ap1 = *(const bh8*)&Pl[w * 16 + l15][32 + g * 8];
        #pragma unroll
        for (int c2 = 0; c2 < 4; ++c2) {
            bh8 bv0 = *(const bh8*)&Vl[c2 * 16 + l15][     g * 8];
            bh8 bv1 = *(const bh8*)&Vl[c2 * 16 + l15][32 + g * 8];
            acc_o[c2] = __builtin_amdgcn_mfma_f32_16x16x32_bf16(ap0, bv0, acc_o[c2], 0, 0, 0);
            acc_o[c2] = __builtin_amdgcn_mfma_f32_16x16x32_bf16(ap1, bv1, acc_o[c2], 0, 0, 0);
        }
    }

    #pragma unroll
    for (int j = 0; j < 4; ++j) {
        float linv = 1.f / l_run[j];
        #pragma unroll
        for (int c2 = 0; c2 < 4; ++c2)
            outb[((size_t)(b * S_ + qd + j)) * D_ + h * DK_ + c2 * 16 + l15] =
                f2bf(acc_o[c2][j] * linv);
    }
}

extern "C" void kernel_launch(void* const* d_in, const int* in_sizes, int n_in,
                              void* d_out, int out_size, void* d_ws, size_t ws_size,
                              hipStream_t stream)
{
    const float* x     = (const float*)d_in[0];
    const int*   pm    = (const int*)  d_in[1];
    const float* tm    = (const float*)d_in[2];
    const float* wq    = (const float*)d_in[3];
    const float* bq    = (const float*)d_in[4];
    const float* wk    = (const float*)d_in[5];
    const float* bk    = (const float*)d_in[6];
    const float* wv    = (const float*)d_in[7];
    const float* bv    = (const float*)d_in[8];
    const float* wp    = (const float*)d_in[9];
    const float* bp    = (const float*)d_in[10];
    const float* w_tb1 = (const float*)d_in[11];
    const float* b_tb1 = (const float*)d_in[12];
    const float* w_tb2 = (const float*)d_in[13];
    const float* b_tb2 = (const float*)d_in[14];

    char* wsb = (char*)d_ws;
    const size_t MB = 1u << 20;
    unsigned short* xb   = (unsigned short*)wsb;              // 8MB; reused as attn out
    unsigned short* wqkv = (unsigned short*)(wsb + 8  * MB);  // 6MB (3072x1024 bf16)
    unsigned short* wtp  = (unsigned short*)(wsb + 14 * MB);  // 2MB
    unsigned short* qw   = (unsigned short*)(wsb + 16 * MB);  // 8MB (B,H,S,DK)
    unsigned short* kw   = (unsigned short*)(wsb + 24 * MB);  // 8MB (B,H,S,DK)
    unsigned short* vtw  = (unsigned short*)(wsb + 32 * MB);  // 8MB (B,H,DK,S)
    float*          bw   = (float*)        (wsb + 40 * MB);   // 8MB f32 (B,S,S)

    cvt_x_kernel<<<2048, 256, 0, stream>>>(x, xb, 524288);
    dim3 gw(16, 16);
    cvt_wt_kernel<<<gw, 256, 0, stream>>>(wq, wqkv);
    cvt_wt_kernel<<<gw, 256, 0, stream>>>(wk, wqkv + 1048576);
    cvt_wt_kernel<<<gw, 256, 0, stream>>>(wv, wqkv + 2097152);
    cvt_wt_kernel<<<gw, 256, 0, stream>>>(wp, wtp);

    dim3 gqkv(32, 48);
    gemm_qkv_kernel<<<gqkv, 256, 0, stream>>>(xb, wqkv, bq, bk, bv, qw, kw, vtw);

    tbias_kernel<<<2048, 256, 0, stream>>>(tm, pm, w_tb1, b_tb1, w_tb2, b_tb2, bw);

    attn_kernel<<<1024, 256, 0, stream>>>(qw, kw, vtw, bw, xb /*out*/);

    dim3 gp(32, 16);
    gemm_proj_kernel<<<gp, 256, 0, stream>>>(xb, wtp, bp, (float*)d_out);
}